// Round 2
// baseline (282.305 us; speedup 1.0000x reference)
//
#include <hip/hip_runtime.h>

#define C0 0.28209479177387814f
#define C1 0.4886025119029199f
#define BLK 256

__device__ __forceinline__ float sigmoidf(float x) {
    return 1.0f / (1.0f + expf(-x));
}

__global__ __launch_bounds__(BLK) void gauss_kernel(
    const float* __restrict__ view_dirs,
    const float* __restrict__ xyz,
    const float* __restrict__ scale_log,
    const float4* __restrict__ rot_quat,
    const float* __restrict__ opacity_logit,
    const float* __restrict__ sh,       // N*12 floats
    float* __restrict__ out_xyz,        // N*3
    float* __restrict__ out_cov,        // N*9
    float* __restrict__ out_rgb,        // N*3
    float* __restrict__ out_op,         // N*1
    int N)
{
    // 18 KB: inputs vd[768] | sl[768] | sh[3072]; overlaid after barrier by cov[2304] | rgb[768]
    __shared__ float smem[4608];
    float* s_vd  = smem;          // 768 floats
    float* s_sl  = smem + 768;    // 768 floats
    float* s_sh  = smem + 1536;   // 3072 floats
    float* s_cov = smem;          // overlay, 2304 floats
    float* s_rgb = smem + 2304;   // overlay, 768 floats

    const int t  = threadIdx.x;
    const int e0 = blockIdx.x * BLK;
    const int nelem = min(BLK, N - e0);
    const int n3 = 3 * nelem;

    // ---- xyz passthrough: pure coalesced float4 copy, no LDS ----
    {
        const float* g = xyz + (size_t)3 * e0;
        float*       o = out_xyz + (size_t)3 * e0;
        int nf4 = n3 >> 2;
        for (int k = t; k < nf4; k += BLK)
            ((float4*)o)[k] = ((const float4*)g)[k];
        int rem = n3 & 3;
        if (t < rem) o[nf4 * 4 + t] = g[nf4 * 4 + t];
    }

    // ---- stage strided inputs into LDS (coalesced float4 loads) ----
    {
        const float* g = view_dirs + (size_t)3 * e0;
        int nf4 = n3 >> 2;
        for (int k = t; k < nf4; k += BLK)
            ((float4*)s_vd)[k] = ((const float4*)g)[k];
        int rem = n3 & 3;
        if (t < rem) s_vd[nf4 * 4 + t] = g[nf4 * 4 + t];
    }
    {
        const float* g = scale_log + (size_t)3 * e0;
        int nf4 = n3 >> 2;
        for (int k = t; k < nf4; k += BLK)
            ((float4*)s_sl)[k] = ((const float4*)g)[k];
        int rem = n3 & 3;
        if (t < rem) s_sl[nf4 * 4 + t] = g[nf4 * 4 + t];
    }
    {
        const float* g = sh + (size_t)12 * e0;
        int nf4 = (12 * nelem) >> 2;  // 12*nelem always divisible by 4
        for (int k = t; k < nf4; k += BLK)
            ((float4*)s_sh)[k] = ((const float4*)g)[k];
    }
    __syncthreads();

    // ---- per-thread compute ----
    const int i = e0 + t;
    const bool active = (t < nelem);
    float cv[9], rgb[3], opac;

    if (active) {
        float4 q  = rot_quat[i];        // already coalesced float4
        float  ol = opacity_logit[i];   // already coalesced scalar

        float vx = s_vd[3 * t + 0], vy = s_vd[3 * t + 1], vz = s_vd[3 * t + 2];
        float sl0 = s_sl[3 * t + 0], sl1 = s_sl[3 * t + 1], sl2 = s_sl[3 * t + 2];
        float4 c0 = ((float4*)s_sh)[3 * t + 0];
        float4 c1 = ((float4*)s_sh)[3 * t + 1];
        float4 c2 = ((float4*)s_sh)[3 * t + 2];

        opac = sigmoidf(ol);

        rgb[0] = sigmoidf(C0 * c0.x - C1 * vy * c0.y + C1 * vz * c0.z - C1 * vx * c0.w);
        rgb[1] = sigmoidf(C0 * c1.x - C1 * vy * c1.y + C1 * vz * c1.z - C1 * vx * c1.w);
        rgb[2] = sigmoidf(C0 * c2.x - C1 * vy * c2.y + C1 * vz * c2.z - C1 * vx * c2.w);

        float nrm = sqrtf(q.x * q.x + q.y * q.y + q.z * q.z + q.w * q.w);
        float inv = 1.0f / fmaxf(nrm, 1e-12f);
        float r = q.x * inv, x = q.y * inv, y = q.z * inv, z = q.w * inv;

        float R00 = 1.0f - 2.0f * (y * y + z * z);
        float R01 = 2.0f * (x * y - r * z);
        float R02 = 2.0f * (x * z + r * y);
        float R10 = 2.0f * (x * y + r * z);
        float R11 = 1.0f - 2.0f * (x * x + z * z);
        float R12 = 2.0f * (y * z - r * x);
        float R20 = 2.0f * (x * z - r * y);
        float R21 = 2.0f * (y * z + r * x);
        float R22 = 1.0f - 2.0f * (x * x + y * y);

        float s0 = expf(sl0), s1 = expf(sl1), s2 = expf(sl2);

        float M00 = R00 * s0, M01 = R01 * s1, M02 = R02 * s2;
        float M10 = R10 * s0, M11 = R11 * s1, M12 = R12 * s2;
        float M20 = R20 * s0, M21 = R21 * s1, M22 = R22 * s2;

        cv[0] = M00 * M00 + M01 * M01 + M02 * M02;
        cv[1] = M00 * M10 + M01 * M11 + M02 * M12;
        cv[2] = M00 * M20 + M01 * M21 + M02 * M22;
        cv[4] = M10 * M10 + M11 * M11 + M12 * M12;
        cv[5] = M10 * M20 + M11 * M21 + M12 * M22;
        cv[8] = M20 * M20 + M21 * M21 + M22 * M22;
        cv[3] = cv[1]; cv[6] = cv[2]; cv[7] = cv[5];

        out_op[i] = opac;               // coalesced scalar store
    }

    __syncthreads();  // all LDS input reads done before overlay

    if (active) {
        #pragma unroll
        for (int k = 0; k < 9; k++) s_cov[9 * t + k] = cv[k];   // stride 9 dw: 2-way, free
        s_rgb[3 * t + 0] = rgb[0];
        s_rgb[3 * t + 1] = rgb[1];
        s_rgb[3 * t + 2] = rgb[2];
    }

    __syncthreads();

    // ---- coalesced float4 stores from LDS ----
    {
        float* g = out_cov + (size_t)9 * e0;
        int nfl = 9 * nelem;
        int nf4 = nfl >> 2;
        for (int k = t; k < nf4; k += BLK)
            ((float4*)g)[k] = ((float4*)s_cov)[k];
        int rem = nfl & 3;
        if (t < rem) g[nf4 * 4 + t] = s_cov[nf4 * 4 + t];
    }
    {
        float* g = out_rgb + (size_t)3 * e0;
        int nf4 = n3 >> 2;
        for (int k = t; k < nf4; k += BLK)
            ((float4*)g)[k] = ((float4*)s_rgb)[k];
        int rem = n3 & 3;
        if (t < rem) g[nf4 * 4 + t] = s_rgb[nf4 * 4 + t];
    }
}

extern "C" void kernel_launch(void* const* d_in, const int* in_sizes, int n_in,
                              void* d_out, int out_size, void* d_ws, size_t ws_size,
                              hipStream_t stream) {
    const float*  view_dirs     = (const float*)d_in[0];
    const float*  xyz           = (const float*)d_in[1];
    const float*  scale_log     = (const float*)d_in[2];
    const float4* rot_quat      = (const float4*)d_in[3];
    const float*  opacity_logit = (const float*)d_in[4];
    const float*  sh            = (const float*)d_in[5];

    int N = in_sizes[4];  // opacity_logit has N elements

    float* out = (float*)d_out;
    float* out_xyz = out;                 // N*3
    float* out_cov = out + (size_t)3 * N; // N*9
    float* out_rgb = out + (size_t)12 * N;// N*3
    float* out_op  = out + (size_t)15 * N;// N

    int grid = (N + BLK - 1) / BLK;
    gauss_kernel<<<grid, BLK, 0, stream>>>(view_dirs, xyz, scale_log, rot_quat,
                                           opacity_logit, sh,
                                           out_xyz, out_cov, out_rgb, out_op, N);
}